// Round 1
// baseline (326.477 us; speedup 1.0000x reference)
//
#include <hip/hip_runtime.h>

// FeaturesEmbedding: out[b, d] = sum_{i : seg[i]==b} table[ids[i], d] * ratings[i]
// seg is sorted -> each segment is a contiguous run; one wave per segment.

#define TOTAL 409600
#define BATCH 4096
#define DIM   64
#define WAVES_PER_BLOCK 4

__global__ __launch_bounds__(256) void features_embedding_kernel(
    const int*   __restrict__ ids,
    const float* __restrict__ ratings,
    const int*   __restrict__ seg,
    const float* __restrict__ table,
    float*       __restrict__ out)
{
    const int wave = threadIdx.x >> 6;          // 0..3
    const int lane = threadIdx.x & 63;          // dim index
    const int b    = blockIdx.x * WAVES_PER_BLOCK + wave;   // segment id
    if (b >= BATCH) return;

    // lower_bound(seg, b): first index with seg[i] >= b
    int lo = 0, hi = TOTAL;
    while (lo < hi) {
        int mid = (lo + hi) >> 1;
        if (seg[mid] < b) lo = mid + 1; else hi = mid;
    }
    int start = lo;
    // lower_bound(seg, b+1): one past the last index with seg[i] == b
    hi = TOTAL;
    while (lo < hi) {
        int mid = (lo + hi) >> 1;
        if (seg[mid] < b + 1) lo = mid + 1; else hi = mid;
    }
    int end = lo;

    // These are wave-uniform; make that explicit so the compiler can use
    // scalar loads / scalar loop control.
    start = __builtin_amdgcn_readfirstlane(start);
    end   = __builtin_amdgcn_readfirstlane(end);

    float acc = 0.0f;
    int r = start;
    constexpr int U = 8;   // 8 independent table-row loads in flight
    for (; r + U <= end; r += U) {
        int   id[U];
        float rt[U];
        #pragma unroll
        for (int u = 0; u < U; ++u) {
            id[u] = ids[r + u];        // wave-uniform -> broadcast load
            rt[u] = ratings[r + u];
        }
        float v[U];
        #pragma unroll
        for (int u = 0; u < U; ++u)
            v[u] = table[(size_t)id[u] * DIM + lane];   // 256 B coalesced row
        #pragma unroll
        for (int u = 0; u < U; ++u)
            acc = fmaf(v[u], rt[u], acc);
    }
    for (; r < end; ++r)
        acc = fmaf(table[(size_t)ids[r] * DIM + lane], ratings[r], acc);

    out[(size_t)b * DIM + lane] = acc;   // covers empty segments with 0
}

extern "C" void kernel_launch(void* const* d_in, const int* in_sizes, int n_in,
                              void* d_out, int out_size, void* d_ws, size_t ws_size,
                              hipStream_t stream) {
    const int*   ids     = (const int*)  d_in[0];
    const float* ratings = (const float*)d_in[1];
    const int*   seg     = (const int*)  d_in[2];
    const float* table   = (const float*)d_in[3];
    float*       out     = (float*)      d_out;

    dim3 grid(BATCH / WAVES_PER_BLOCK);   // 1024 blocks x 4 waves = 4096 segments
    dim3 block(256);
    features_embedding_kernel<<<grid, block, 0, stream>>>(ids, ratings, seg, table, out);
}

// Round 2
// 316.684 us; speedup vs baseline: 1.0309x; 1.0309x over previous
//
#include <hip/hip_runtime.h>

// out[b, d] = sum_{i : seg[i]==b} table[ids[i], d] * ratings[i]
// seg sorted -> contiguous runs. Two kernels:
//  1) seg_offsets: scatter run boundaries into offsets[BATCH+1] (in d_ws)
//  2) embed_bag:   one wave per segment; 4 rows per wave-load via float4;
//                  shfl-xor reduce across the 4 row-groups; lanes 0-15 store.

#define TOTAL 409600
#define BATCH 4096
#define DIM   64

__global__ __launch_bounds__(256) void seg_offsets_kernel(
    const int* __restrict__ seg, int* __restrict__ offsets)
{
    int i = blockIdx.x * blockDim.x + threadIdx.x;
    if (i >= TOTAL) return;
    int cur  = seg[i];
    int prev = (i == 0) ? -1 : seg[i - 1];
    for (int b = prev + 1; b <= cur; ++b) offsets[b] = i;   // lower_bound(seg, b)
    if (i == TOTAL - 1) {
        for (int b = cur + 1; b <= BATCH; ++b) offsets[b] = TOTAL;
    }
}

__global__ __launch_bounds__(256) void embed_bag_kernel(
    const int*   __restrict__ ids,
    const float* __restrict__ ratings,
    const int*   __restrict__ offsets,
    const float* __restrict__ table,
    float*       __restrict__ out)
{
    const int wave = threadIdx.x >> 6;
    const int lane = threadIdx.x & 63;
    const int b    = blockIdx.x * 4 + wave;     // segment id
    const int grp  = lane >> 4;                 // which of 4 rows in a quad-step
    const int col  = lane & 15;                 // which float4 of the 64-dim row

    const int start = offsets[b];
    const int end   = offsets[b + 1];
    const int n     = end - start;

    float4 acc = make_float4(0.f, 0.f, 0.f, 0.f);

    constexpr int U = 4;                        // quad-steps in flight (16 rows)
    const int full = start + (n / (4 * U)) * (4 * U);

    // main loop: no guards, 16 independent 1KB row-gathers in flight
    for (int base = start; base < full; base += 4 * U) {
        int   id[U];
        float rt[U];
        #pragma unroll
        for (int u = 0; u < U; ++u) {
            int row = base + 4 * u + grp;
            id[u] = ids[row];                   // 4 consecutive ints per wave
            rt[u] = ratings[row];
        }
        #pragma unroll
        for (int u = 0; u < U; ++u) {
            const float4 v = ((const float4*)(table + (size_t)id[u] * DIM))[col];
            acc.x = fmaf(v.x, rt[u], acc.x);
            acc.y = fmaf(v.y, rt[u], acc.y);
            acc.z = fmaf(v.z, rt[u], acc.z);
            acc.w = fmaf(v.w, rt[u], acc.w);
        }
    }

    // tail: up to 15 rows, exec-masked (no wasted fetches)
    for (int base = full; base < end; base += 4) {
        int row = base + grp;
        if (row < end) {
            int   id = ids[row];
            float rt = ratings[row];
            const float4 v = ((const float4*)(table + (size_t)id * DIM))[col];
            acc.x = fmaf(v.x, rt, acc.x);
            acc.y = fmaf(v.y, rt, acc.y);
            acc.z = fmaf(v.z, rt, acc.z);
            acc.w = fmaf(v.w, rt, acc.w);
        }
    }

    // reduce the 4 row-groups (lanes xor 16, xor 32) — deterministic
    #pragma unroll
    for (int m = 16; m <= 32; m <<= 1) {
        acc.x += __shfl_xor(acc.x, m);
        acc.y += __shfl_xor(acc.y, m);
        acc.z += __shfl_xor(acc.z, m);
        acc.w += __shfl_xor(acc.w, m);
    }
    if (grp == 0) {
        ((float4*)(out + (size_t)b * DIM))[col] = acc;   // 16 lanes x 16B = full row
    }
}

extern "C" void kernel_launch(void* const* d_in, const int* in_sizes, int n_in,
                              void* d_out, int out_size, void* d_ws, size_t ws_size,
                              hipStream_t stream) {
    const int*   ids     = (const int*)  d_in[0];
    const float* ratings = (const float*)d_in[1];
    const int*   seg     = (const int*)  d_in[2];
    const float* table   = (const float*)d_in[3];
    float*       out     = (float*)      d_out;
    int*         offsets = (int*)        d_ws;   // (BATCH+1) ints

    seg_offsets_kernel<<<(TOTAL + 255) / 256, 256, 0, stream>>>(seg, offsets);
    embed_bag_kernel<<<BATCH / 4, 256, 0, stream>>>(ids, ratings, offsets, table, out);
}